// Round 7
// baseline (179.627 us; speedup 1.0000x reference)
//
#include <hip/hip_runtime.h>

typedef __bf16 bf8 __attribute__((ext_vector_type(8)));
typedef float f4 __attribute__((ext_vector_type(4)));
typedef float f32x16 __attribute__((ext_vector_type(16)));
typedef unsigned short us4 __attribute__((ext_vector_type(4)));
typedef unsigned int u32x4 __attribute__((ext_vector_type(4)));

#define MFMA16(a,b,c) __builtin_amdgcn_mfma_f32_16x16x32_bf16((a),(b),(c),0,0,0)
#define MFMA32(a,b,c) __builtin_amdgcn_mfma_f32_32x32x16_bf16((a),(b),(c),0,0,0)

#define BLOCK 512
#define NWAVE 8

__device__ __forceinline__ unsigned short f2bfu(float f){
  __bf16 h = (__bf16)f;
  union { __bf16 b; unsigned short u; } v; v.b = h; return v.u;
}
__device__ __forceinline__ float ubfu(unsigned int u16){
  union { unsigned int i; float f; } v; v.i = u16 << 16; return v.f;
}

// Wave-local LDS fence (fused fallback kernel only).
__device__ __forceinline__ void wfence(){
  asm volatile("s_waitcnt lgkmcnt(0)" ::: "memory");
}

// Scheduler cage (validated r5): stops cross-layer hoisting of loop-invariant
// weight ds_reads -> elastic register demand -> spill (r3/r4: 1.2-1.7 GB).
#define SBAR() __builtin_amdgcn_sched_barrier(0)

// ---------------- old 16x16 layout (fused fallback kernel only) ------------
#define OFF_W1   0
#define OFF_W2   2048
#define OFF_W3   6144
#define OFF_CW1  7168
#define OFF_CW2  8192
#define OFF_CW3  12288
#define OFF_CW4  16384
#define OFF_ACT  17408
#define ACT_STRIDE 72
#define SMEM_US  (17408 + NWAVE*16*ACT_STRIDE)

#define BO_B1  0
#define BO_B2  64
#define BO_B3  128
#define BO_CB1 144
#define BO_CB2 208
#define BO_CB3 272
#define BO_CB4 336

template<int FIN,int FOUT,int KS,int MT>
__device__ __forceinline__ void stage_w(const float* w, unsigned short* dst){
  const int total = KS*MT*512;
  for (int e = threadIdx.x; e < total; e += BLOCK){
    int chunk = e >> 9;
    int s = chunk / MT, t = chunk % MT;
    int le = e & 511;
    int lane = le >> 3, j = le & 7;
    int q = lane >> 4, m = lane & 15;
    int i = s*32 + q*8 + j;
    int o = t*16 + m;
    dst[e] = (i < FIN && o < FOUT) ? f2bfu(w[i*FOUT + o]) : (unsigned short)0;
  }
}

__device__ __forceinline__ void stage_cw1(const float* w, unsigned short* dst){
  for (int e = threadIdx.x; e < 1024; e += BLOCK){
    int t = e >> 8;
    int le = e & 255;
    int lane = le >> 3, j = e & 7;
    int q = lane >> 4, m = lane & 15;
    dst[e] = f2bfu(w[(q*8+j)*64 + t*16 + m]);
  }
}

__device__ __forceinline__ void layer64(const unsigned short* wlds, const unsigned short* bias,
                                        unsigned short* act, int lane, bool relu){
  const int q = lane >> 4, m = lane & 15;
  bf8 b0 = *(const bf8*)(act + m*ACT_STRIDE + q*8);
  bf8 b1 = *(const bf8*)(act + m*ACT_STRIDE + 32 + q*8);
  f4 acc[4];
#pragma unroll
  for (int t = 0; t < 4; ++t){
    f4 c = {0.f,0.f,0.f,0.f};
    c = MFMA16(*(const bf8*)(wlds + ((0*4+t)*64+lane)*8), b0, c);
    c = MFMA16(*(const bf8*)(wlds + ((1*4+t)*64+lane)*8), b1, c);
    acc[t] = c;
  }
#pragma unroll
  for (int t = 0; t < 4; ++t){
    us4 bb = *(const us4*)(bias + t*16 + q*4);
    us4 pk;
#pragma unroll
    for (int r = 0; r < 4; ++r){
      float v = acc[t][r] + ubfu(bb[r]);
      if (relu) v = fmaxf(v, 0.f);
      pk[r] = f2bfu(v);
    }
    *(us4*)(act + m*ACT_STRIDE + t*16 + q*4) = pk;
  }
}

#define STAGE_ALL_WEIGHTS()                                                  \
  stage_w<32,64,1,4>(w1,  smem+OFF_W1);                                      \
  stage_w<64,64,2,4>(w2,  smem+OFF_W2);                                      \
  stage_w<64,16,2,1>(w3,  smem+OFF_W3);                                      \
  stage_cw1(cw1, smem+OFF_CW1);                                              \
  stage_w<64,64,2,4>(cw2, smem+OFF_CW2);                                     \
  stage_w<64,64,2,4>(cw3, smem+OFF_CW3);                                     \
  stage_w<64, 3,2,1>(cw4, smem+OFF_CW4);                                     \
  {                                                                          \
    int t = threadIdx.x;                                                     \
    if (t < 64){                                                             \
      sbias[BO_B1 +t] = f2bfu(b1[t]);                                        \
      sbias[BO_B2 +t] = f2bfu(b2[t]);                                        \
      sbias[BO_CB1+t] = f2bfu(cb1[t]);                                       \
      sbias[BO_CB2+t] = f2bfu(cb2[t]);                                       \
      sbias[BO_CB3+t] = f2bfu(cb3[t]);                                       \
    }                                                                        \
    if (t < 16) sbias[BO_B3+t] = f2bfu(b3[t]);                               \
    if (t < 3)  sbias[BO_CB4+t] = f2bfu(cb4[t]);                             \
  }

#define MLP_BODY(bfrag, gp)                                                  \
    {                                                                        \
      f4 acc[4];                                                             \
      _Pragma("unroll")                                                      \
      for (int t = 0; t < 4; ++t){                                           \
        f4 c = {0.f,0.f,0.f,0.f};                                            \
        acc[t] = MFMA16(*(const bf8*)(smem + OFF_W1 + (t*64+lane)*8), bfrag, c);\
      }                                                                      \
      _Pragma("unroll")                                                      \
      for (int t = 0; t < 4; ++t){                                           \
        us4 bb = *(const us4*)(sbias + BO_B1 + t*16 + q*4);                  \
        us4 pk;                                                              \
        _Pragma("unroll")                                                    \
        for (int r = 0; r < 4; ++r){                                         \
          float v = fmaxf(acc[t][r] + ubfu(bb[r]), 0.f);                     \
          pk[r] = f2bfu(v);                                                  \
        }                                                                    \
        *(us4*)(act + m*ACT_STRIDE + t*16 + q*4) = pk;                       \
      }                                                                      \
    }                                                                        \
    wfence();                                                                \
    layer64(smem+OFF_W2, sbias+BO_B2, act, lane, true);                      \
    wfence();                                                                \
    {                                                                        \
      bf8 b0 = *(const bf8*)(act + m*ACT_STRIDE + q*8);                      \
      bf8 b1 = *(const bf8*)(act + m*ACT_STRIDE + 32 + q*8);                 \
      f4 c = {0.f,0.f,0.f,0.f};                                              \
      c = MFMA16(*(const bf8*)(smem + OFF_W3 + lane*8), b0, c);              \
      c = MFMA16(*(const bf8*)(smem + OFF_W3 + (64+lane)*8), b1, c);         \
      us4 bb = *(const us4*)(sbias + BO_B3 + q*4);                           \
      us4 pk;                                                                \
      float d0 = 0.f;                                                        \
      _Pragma("unroll")                                                      \
      for (int r = 0; r < 4; ++r){                                           \
        float v = c[r] + ubfu(bb[r]);                                        \
        if (r == 0) d0 = v;                                                  \
        pk[r] = f2bfu(v);                                                    \
      }                                                                      \
      if (q == 0 && gp < nB) out[gp] = expf(d0);                             \
      *(us4*)(act + m*ACT_STRIDE + q*4) = pk;                                \
    }                                                                        \
    wfence();                                                                \
    {                                                                        \
      bf8 bc, aw[4];                                                         \
      if (q < 2){                                                            \
        bc = *(const bf8*)(act + m*ACT_STRIDE + q*8);                        \
        _Pragma("unroll")                                                    \
        for (int t = 0; t < 4; ++t)                                          \
          aw[t] = *(const bf8*)(smem + OFF_CW1 + (t*32+lane)*8);             \
      } else {                                                               \
        _Pragma("unroll")                                                    \
        for (int j = 0; j < 8; ++j) bc[j] = (__bf16)0.f;                     \
        _Pragma("unroll")                                                    \
        for (int t = 0; t < 4; ++t) aw[t] = bc;                              \
      }                                                                      \
      f4 acc[4];                                                             \
      _Pragma("unroll")                                                      \
      for (int t = 0; t < 4; ++t){                                           \
        f4 c = {0.f,0.f,0.f,0.f};                                            \
        acc[t] = MFMA16(aw[t], bc, c);                                       \
      }                                                                      \
      _Pragma("unroll")                                                      \
      for (int t = 0; t < 4; ++t){                                           \
        us4 bb = *(const us4*)(sbias + BO_CB1 + t*16 + q*4);                 \
        us4 pk;                                                              \
        _Pragma("unroll")                                                    \
        for (int r = 0; r < 4; ++r){                                         \
          float v = fmaxf(acc[t][r] + ubfu(bb[r]), 0.f);                     \
          pk[r] = f2bfu(v);                                                  \
        }                                                                    \
        *(us4*)(act + m*ACT_STRIDE + t*16 + q*4) = pk;                       \
      }                                                                      \
    }                                                                        \
    wfence();                                                                \
    layer64(smem+OFF_CW2, sbias+BO_CB2, act, lane, true);                    \
    wfence();                                                                \
    layer64(smem+OFF_CW3, sbias+BO_CB3, act, lane, true);                    \
    wfence();                                                                \
    {                                                                        \
      bf8 b0 = *(const bf8*)(act + m*ACT_STRIDE + q*8);                      \
      bf8 b1 = *(const bf8*)(act + m*ACT_STRIDE + 32 + q*8);                 \
      f4 c = {0.f,0.f,0.f,0.f};                                              \
      c = MFMA16(*(const bf8*)(smem + OFF_CW4 + lane*8), b0, c);             \
      c = MFMA16(*(const bf8*)(smem + OFF_CW4 + (64+lane)*8), b1, c);        \
      if (q == 0 && gp < nB){                                                \
        _Pragma("unroll")                                                    \
        for (int r = 0; r < 3; ++r){                                         \
          float v = c[r] + ubfu(sbias[BO_CB4 + r]);                          \
          out[nB + gp*3 + r] = 1.f/(1.f + expf(-v));                         \
        }                                                                    \
      }                                                                      \
    }                                                                        \
    wfence();

// ---------------------------------------------------------------------------
// Table prepack: tables f32x2 -> packed bf16x2 uint, once. Halves hash-phase
// staging bytes and removes cvt/pack VALU from every hash block's prologue.
// ---------------------------------------------------------------------------
__global__ __launch_bounds__(512) void tab_pack(
    const float* __restrict__ tab, unsigned int* __restrict__ tp)
{
  int e = blockIdx.x*512 + threadIdx.x;     // grid 512 -> 262144 entries
  float2 v = ((const float2*)tab)[e];
  tp[e] = ((unsigned)f2bfu(v.y) << 16) | (unsigned)f2bfu(v.x);
}

// ---------------------------------------------------------------------------
// Phase A: per-level hash encode, full table in LDS, 2-pt unroll (r6, +5us).
// v3: staging from prepacked u32 table via u32x4 vector copies.
// ---------------------------------------------------------------------------
#define CH 16384

#define HASH_BODY_COMMON                                                     \
  const int res = sres[lvl];                                                 \
  const float sc = 0.5f*(float)(res-1);                                      \
  const bool dense = (lvl < 3);                                              \
  unsigned int* fout = feat + (size_t)lvl * (size_t)nB;                      \
  auto body = [&](int p){                                                    \
    const float px = xin[p*3+0], py = xin[p*3+1], pz = xin[p*3+2];           \
    const float xs=(px+1.f)*sc, ys=(py+1.f)*sc, zs=(pz+1.f)*sc;              \
    const float fx=floorf(xs), fy=floorf(ys), fz=floorf(zs);                 \
    const float wx=xs-fx, wy=ys-fy, wz=zs-fz;                                \
    int ix0=min(max((int)fx,0),res-1);                                       \
    int iy0=min(max((int)fy,0),res-1);                                       \
    int iz0=min(max((int)fz,0),res-1);                                       \
    int ix1=min(ix0+1,res-1), iy1=min(iy0+1,res-1), iz1=min(iz0+1,res-1);    \
    unsigned X0,X1,Y0,Y1,Z0,Z1;                                              \
    if (dense){                                                              \
      X0=(unsigned)ix0;            X1=(unsigned)ix1;                         \
      Y0=(unsigned)(res*iy0);      Y1=(unsigned)(res*iy1);                   \
      Z0=(unsigned)(res*res*iz0);  Z1=(unsigned)(res*res*iz1);               \
    } else {                                                                 \
      X0=(unsigned)ix0;                 X1=(unsigned)ix1;                    \
      Y0=(unsigned)iy0*2654435761u;     Y1=(unsigned)iy1*2654435761u;        \
      Z0=(unsigned)iz0*805459861u;      Z1=(unsigned)iz1*805459861u;         \
    }                                                                        \
    const float wx0=1.f-wx, wy0=1.f-wy, wz0=1.f-wz;                          \
    float f0=0.f, f1=0.f;                                                    \
    _Pragma("unroll")                                                        \
    for (int c = 0; c < 8; ++c){                                             \
      unsigned xc = (c&1)?X1:X0;                                             \
      unsigned yc = (c&2)?Y1:Y0;                                             \
      unsigned zc = (c&4)?Z1:Z0;                                             \
      unsigned idx = dense ? (xc+yc+zc) : ((xc^yc^zc)&16383u);               \
      unsigned tv = stab[idx];                                               \
      float wc = ((c&1)?wx:wx0) * ((c&2)?wy:wy0) * ((c&4)?wz:wz0);           \
      f0 += wc*ubfu(tv << 16);                                               \
      f1 += wc*ubfu(tv & 0xffff0000u);                                       \
    }                                                                        \
    fout[p] = ((unsigned)f2bfu(f1) << 16) | (unsigned)f2bfu(f0);             \
  };                                                                         \
  int pend = (blockIdx.x + 1) * CH; if (pend > nB) pend = nB;                \
  int p = blockIdx.x*CH + threadIdx.x;                                       \
  for (; p + 512 < pend; p += 1024){ body(p); body(p + 512); }               \
  if (p < pend) body(p);

__global__ __launch_bounds__(512) void hash_phase(
    const float* __restrict__ xin, const unsigned int* __restrict__ tabp,
    unsigned int* __restrict__ feat, int nB)
{
  __shared__ __align__(16) unsigned int stab[16384];
  __shared__ int sres[16];
  const int lvl = blockIdx.y;
  {
    const u32x4* t4 = (const u32x4*)(tabp + (lvl<<14));
    u32x4* s4 = (u32x4*)stab;
    for (int e = threadIdx.x; e < 4096; e += 512) s4[e] = t4[e];
    if (threadIdx.x < 16){
      const int R[16] = {16,20,25,32,40,50,64,80,101,128,161,203,256,322,406,512};
      sres[threadIdx.x] = R[threadIdx.x];
    }
  }
  __syncthreads();
  HASH_BODY_COMMON
}

// fallback variant: stage from f32 tables directly (ws fits feat only)
__global__ __launch_bounds__(512) void hash_phase_f32(
    const float* __restrict__ xin, const float* __restrict__ tab,
    unsigned int* __restrict__ feat, int nB)
{
  __shared__ __align__(16) unsigned int stab[16384];
  __shared__ int sres[16];
  const int lvl = blockIdx.y;
  {
    const float2* t2 = (const float2*)tab + (lvl<<14);
    for (int e = threadIdx.x; e < 16384; e += 512){
      float2 v = t2[e];
      stab[e] = ((unsigned)f2bfu(v.y) << 16) | (unsigned)f2bfu(v.x);
    }
    if (threadIdx.x < 16){
      const int R[16] = {16,20,25,32,40,50,64,80,101,128,161,203,256,322,406,512};
      sres[threadIdx.x] = R[threadIdx.x];
    }
  }
  __syncthreads();
  HASH_BODY_COMMON
}

// ===========================================================================
// Phase B v8: 32x32x16 MFMA, register-resident activations, SBAR cage (r5).
// r6 post-mortem: bias-rank-1-MFMA regressed (72 vs 69) -> reverted to f32
// LDS bias C-init. NEW: exposed-LDS-latency fix — each layer began with a
// ~120cy lgkmcnt stall on its A-frags (~10/iter, the missing ~1300 cyc/iter).
// Now: small layers' frags persistent in VGPRs (w1/w3/cw1/cw4 = 14 frags,
// 56 regs, bounded by hand); big layers (W2/CW2/CW3) prefetched >=1 full
// region ahead of use. Hand-counted peak ~214 regs < 256 cap at (512,2).
// ===========================================================================

// 32x32 A-frag staging layout (ushort offsets)
#define W32_W1   0        // MT2 KT2: 2048
#define W32_W2   2048     // MT2 KT4: 4096
#define W32_W3   6144     // MT1 KT4: 2048 (FOUT=16 padded to 32)
#define W32_CW1  8192     // MT2 KT1: 1024
#define W32_CW2  9216     // MT2 KT4: 4096
#define W32_CW3  13312    // MT2 KT4: 4096
#define W32_CW4  17408    // MT1 KT4: 2048 (FOUT=3 padded)
#define W32_TOT  19456

// f32 bias offsets
#define SB_B1  0
#define SB_B2  64
#define SB_CB1 128
#define SB_CB2 192
#define SB_CB3 256
#define SB_B3  320   // 32 entries (16 real + 16 zero)
#define SB_CB4 352   // 32 entries (3 real + zeros)

// A-frag stager: frag = mt*KT+kt; lane l elem j -> W[kt*16+(l>>5)*8+j][mt*32+(l&31)]
template<int FIN,int FOUT,int MT,int KT>
__device__ __forceinline__ void stage32(const float* w, unsigned short* dst){
  const int total = MT*KT*512;
  for (int e = threadIdx.x; e < total; e += BLOCK){
    int frag = e >> 9;
    int mt = frag / KT, kt = frag % KT;
    int l  = (e >> 3) & 63, j = e & 7;
    int i  = kt*16 + ((l >> 5) << 3) + j;
    int o  = mt*32 + (l & 31);
    dst[e] = (i < FIN && o < FOUT) ? f2bfu(w[i*FOUT + o]) : (unsigned short)0;
  }
}

__device__ __forceinline__ unsigned pk2(float x, float y){
  typedef __bf16 bf2v __attribute__((ext_vector_type(2)));
  union { bf2v b; unsigned u; } v;
  v.b[0] = (__bf16)x; v.b[1] = (__bf16)y;
  return v.u;
}

__device__ __forceinline__ bf8 mkbf8(unsigned d0, unsigned d1, unsigned d2, unsigned d3){
  union { u32x4 u; bf8 b; } v;
  v.u[0] = d0; v.u[1] = d1; v.u[2] = d2; v.u[3] = d3;
  return v.b;
}

// Exchange 32-lane halves: x = {a_lo, b_lo}, y = {a_hi, b_hi}.
__device__ __forceinline__ void swap_half(unsigned a, unsigned b, unsigned& x, unsigned& y){
#if __has_builtin(__builtin_amdgcn_permlane32_swap)
  auto r = __builtin_amdgcn_permlane32_swap(a, b, false, false);
  x = r[0]; y = r[1];
#else
  unsigned sa = (unsigned)__shfl_xor((int)a, 32, 64);
  unsigned sb = (unsigned)__shfl_xor((int)b, 32, 64);
  bool lo = (threadIdx.x & 32) == 0;
  x = lo ? a : sb;
  y = lo ? sa : b;
#endif
}

// bias C-init for one 32-row M-tile: reg r -> row (r&3)+8*(r>>2)+4h
__device__ __forceinline__ f32x16 bias16(const float* sb, int h4){
  f4 c0 = *(const f4*)(sb + h4);
  f4 c1 = *(const f4*)(sb + 8  + h4);
  f4 c2 = *(const f4*)(sb + 16 + h4);
  f4 c3 = *(const f4*)(sb + 24 + h4);
  f32x16 c;
#pragma unroll
  for (int r = 0; r < 4; ++r){
    c[r] = c0[r]; c[4+r] = c1[r]; c[8+r] = c2[r]; c[12+r] = c3[r];
  }
  return c;
}

// 64-wide layer output (a0=rows 0..31, a1=rows 32..63) -> relu -> 4 B-frags
__device__ __forceinline__ void trans2(const f32x16 a0, const f32x16 a1, bf8* B){
  unsigned p0[8], p1[8];
#pragma unroll
  for (int p = 0; p < 8; ++p){
    p0[p] = pk2(fmaxf(a0[2*p], 0.f), fmaxf(a0[2*p+1], 0.f));
    p1[p] = pk2(fmaxf(a1[2*p], 0.f), fmaxf(a1[2*p+1], 0.f));
  }
#pragma unroll
  for (int o = 0; o < 2; ++o){
    unsigned x0,y0,x1,y1;
    swap_half(p0[4*o+0], p0[4*o+2], x0, y0);
    swap_half(p0[4*o+1], p0[4*o+3], x1, y1);
    B[o] = mkbf8(x0, x1, y0, y1);
    swap_half(p1[4*o+0], p1[4*o+2], x0, y0);
    swap_half(p1[4*o+1], p1[4*o+3], x1, y1);
    B[2+o] = mkbf8(x0, x1, y0, y1);
  }
}

#define PTS_PER_BLOCK 1024
#define M_ITERS 4

__global__ __launch_bounds__(BLOCK, 2) void mlp32_phase(
    const unsigned int* __restrict__ feat,
    const float* __restrict__ w1,  const float* __restrict__ b1,
    const float* __restrict__ w2,  const float* __restrict__ b2,
    const float* __restrict__ w3,  const float* __restrict__ b3,
    const float* __restrict__ cw1, const float* __restrict__ cb1,
    const float* __restrict__ cw2, const float* __restrict__ cb2,
    const float* __restrict__ cw3, const float* __restrict__ cb3,
    const float* __restrict__ cw4, const float* __restrict__ cb4,
    float* __restrict__ out, int nB)
{
  __shared__ __align__(16) unsigned short sw[W32_TOT];
  __shared__ __align__(16) float sbf[384];
  stage32<32,64,2,2>(w1,  sw+W32_W1);
  stage32<64,64,2,4>(w2,  sw+W32_W2);
  stage32<64,16,1,4>(w3,  sw+W32_W3);
  stage32<16,64,2,1>(cw1, sw+W32_CW1);
  stage32<64,64,2,4>(cw2, sw+W32_CW2);
  stage32<64,64,2,4>(cw3, sw+W32_CW3);
  stage32<64, 3,1,4>(cw4, sw+W32_CW4);
  {
    int t = threadIdx.x;
    if (t < 64){
      sbf[SB_B1 +t] = b1[t];
      sbf[SB_B2 +t] = b2[t];
      sbf[SB_CB1+t] = cb1[t];
      sbf[SB_CB2+t] = cb2[t];
      sbf[SB_CB3+t] = cb3[t];
    }
    if (t >= 64 && t < 96)  sbf[SB_B3  + t-64] = (t-64 < 16) ? b3[t-64]  : 0.f;
    if (t >= 96 && t < 128) sbf[SB_CB4 + t-96] = (t-96 < 3)  ? cb4[t-96] : 0.f;
  }
  __syncthreads();

  const int l  = threadIdx.x & 63, wv = threadIdx.x >> 6;
  const int h  = l >> 5, n = l & 31, h4 = h << 2;
  const int base0 = blockIdx.x * PTS_PER_BLOCK + wv*32 + n;

#define FR(off, frag) (*(const bf8*)(sw + (off) + ((frag) << 9) + (l << 3)))
#define LOADF(d0, d1, g) {                                                   \
    int gg = min((g), nB-1);                                                 \
    _Pragma("unroll")                                                        \
    for (int d = 0; d < 4; ++d){                                             \
      d0[d] = feat[(size_t)(h4 + d)*(size_t)nB + gg];                        \
      d1[d] = feat[(size_t)(8 + h4 + d)*(size_t)nB + gg];                    \
    } }

  // persistent small-layer frags (14 frags = 56 VGPR, bounded by hand)
  bf8 w1f[4], w3f[4], cw1f[2], cw4f[4];
#pragma unroll
  for (int t = 0; t < 4; ++t) w1f[t]  = FR(W32_W1,  t);
#pragma unroll
  for (int t = 0; t < 4; ++t) w3f[t]  = FR(W32_W3,  t);
  cw1f[0] = FR(W32_CW1, 0); cw1f[1] = FR(W32_CW1, 1);
#pragma unroll
  for (int t = 0; t < 4; ++t) cw4f[t] = FR(W32_CW4, t);

  u32x4 f0, f1, nf0, nf1;
  LOADF(f0, f1, base0)

  for (int it = 0; it < M_ITERS; ++it){
    const int gp = base0 + it*256;
    bf8 B[4];
    B[0] = mkbf8(f0[0], f0[1], f0[2], f0[3]);
    B[1] = mkbf8(f1[0], f1[1], f1[2], f1[3]);
    SBAR();

    // Region L1: compute L1 (persistent w1f); issue W2 frag loads for L2
    bf8 wf[8];
#pragma unroll
    for (int k = 0; k < 8; ++k) wf[k] = FR(W32_W2, k);
    f32x16 a0 = bias16(sbf + SB_B1,      h4);
    f32x16 a1 = bias16(sbf + SB_B1 + 32, h4);
    a0 = MFMA32(w1f[0], B[0], a0);
    a0 = MFMA32(w1f[1], B[1], a0);
    a1 = MFMA32(w1f[2], B[0], a1);
    a1 = MFMA32(w1f[3], B[1], a1);
    SBAR();

    if (it + 1 < M_ITERS){ LOADF(nf0, nf1, gp + 256) }
    SBAR();

    trans2(a0, a1, B);
    SBAR();

    // Region L2: compute with wf (loaded last region)
    a0 = bias16(sbf + SB_B2,      h4);
    a1 = bias16(sbf + SB_B2 + 32, h4);
#pragma unroll
    for (int kt = 0; kt < 4; ++kt){
      a0 = MFMA32(wf[kt],   B[kt], a0);
      a1 = MFMA32(wf[4+kt], B[kt], a1);
    }
    SBAR();
    trans2(a0, a1, B);
    SBAR();

    // Region L3: persistent w3f; issue CW2 frag loads for C2
    bf8 wg[8];
#pragma unroll
    for (int k = 0; k < 8; ++k) wg[k] = FR(W32_CW2, k);
    f32x16 ad = bias16(sbf + SB_B3, h4);
#pragma unroll
    for (int kt = 0; kt < 4; ++kt) ad = MFMA32(w3f[kt], B[kt], ad);
    SBAR();
    if (h == 0 && gp < nB) out[gp] = expf(ad[0]);
    {
      unsigned q0 = pk2(ad[0], ad[1]);
      unsigned q1 = pk2(ad[2], ad[3]);
      unsigned q2 = pk2(ad[4], ad[5]);
      unsigned q3 = pk2(ad[6], ad[7]);
      unsigned x0,y0,x1,y1;
      swap_half(q0, q2, x0, y0);
      swap_half(q1, q3, x1, y1);
      B[0] = mkbf8(x0, x1, y0, y1);
    }
    SBAR();

    // Region C1: persistent cw1f
    a0 = bias16(sbf + SB_CB1,      h4);
    a1 = bias16(sbf + SB_CB1 + 32, h4);
    a0 = MFMA32(cw1f[0], B[0], a0);
    a1 = MFMA32(cw1f[1], B[0], a1);
    SBAR();
    trans2(a0, a1, B);
    SBAR();

    // Region C2: compute with wg (loaded 2 regions ago); issue CW3 into wf
#pragma unroll
    for (int k = 0; k < 8; ++k) wf[k] = FR(W32_CW3, k);
    a0 = bias16(sbf + SB_CB2,      h4);
    a1 = bias16(sbf + SB_CB2 + 32, h4);
#pragma unroll
    for (int kt = 0; kt < 4; ++kt){
      a0 = MFMA32(wg[kt],   B[kt], a0);
      a1 = MFMA32(wg[4+kt], B[kt], a1);
    }
    SBAR();
    trans2(a0, a1, B);
    SBAR();

    // Region C3: compute with wf (loaded last region)
    a0 = bias16(sbf + SB_CB3,      h4);
    a1 = bias16(sbf + SB_CB3 + 32, h4);
#pragma unroll
    for (int kt = 0; kt < 4; ++kt){
      a0 = MFMA32(wf[kt],   B[kt], a0);
      a1 = MFMA32(wf[4+kt], B[kt], a1);
    }
    SBAR();
    trans2(a0, a1, B);
    SBAR();

    // Region C4: persistent cw4f; sigmoid
    f32x16 ac = bias16(sbf + SB_CB4, h4);
#pragma unroll
    for (int kt = 0; kt < 4; ++kt) ac = MFMA32(cw4f[kt], B[kt], ac);
    SBAR();
    if (h == 0 && gp < nB){
      out[nB + gp*3 + 0] = 1.f/(1.f + expf(-ac[0]));
      out[nB + gp*3 + 1] = 1.f/(1.f + expf(-ac[1]));
      out[nB + gp*3 + 2] = 1.f/(1.f + expf(-ac[2]));
    }
    SBAR();

    if (it + 1 < M_ITERS){ f0 = nf0; f1 = nf1; }
  }
#undef FR
#undef LOADF
}

// ---------------------------------------------------------------------------
// Fallback: fused kernel (used only if workspace too small).
// ---------------------------------------------------------------------------
__global__ __launch_bounds__(BLOCK) void nerf_fused(
    const float* __restrict__ xin, const float* __restrict__ tab,
    const float* __restrict__ w1,  const float* __restrict__ b1,
    const float* __restrict__ w2,  const float* __restrict__ b2,
    const float* __restrict__ w3,  const float* __restrict__ b3,
    const float* __restrict__ cw1, const float* __restrict__ cb1,
    const float* __restrict__ cw2, const float* __restrict__ cb2,
    const float* __restrict__ cw3, const float* __restrict__ cb3,
    const float* __restrict__ cw4, const float* __restrict__ cb4,
    float* __restrict__ out, int nB)
{
  __shared__ __align__(16) unsigned short smem[SMEM_US];
  __shared__ __align__(16) unsigned short sbias[344];
  __shared__ int sres[16];
  STAGE_ALL_WEIGHTS();
  if (threadIdx.x < 16){
    const int R[16] = {16,20,25,32,40,50,64,80,101,128,161,203,256,322,406,512};
    sres[threadIdx.x] = R[threadIdx.x];
  }
  __syncthreads();

  const int lane = threadIdx.x & 63, wv = threadIdx.x >> 6;
  const int q = lane >> 4, m = lane & 15;
  unsigned short* act = smem + OFF_ACT + wv*16*ACT_STRIDE;

  int res_[4];
#pragma unroll
  for (int d = 0; d < 4; ++d) res_[d] = sres[4*q + d];

  for (int it = 0; it < 4; ++it){
    const int gp  = blockIdx.x*BLOCK + wv*64 + it*16 + m;
    const int gpl = min(gp, nB-1);
    const float px = xin[gpl*3+0];
    const float py = xin[gpl*3+1];
    const float pz = xin[gpl*3+2];

    bf8 bfrag;
#pragma unroll
    for (int d = 0; d < 4; ++d){
      const int lvl = 4*q + d;
      const int res = res_[d];
      const float sc = 0.5f*(float)(res-1);
      const float xs=(px+1.f)*sc, ys=(py+1.f)*sc, zs=(pz+1.f)*sc;
      const float fx=floorf(xs), fy=floorf(ys), fz=floorf(zs);
      const float wx=xs-fx, wy=ys-fy, wz=zs-fz;
      int ix0=min(max((int)fx,0),res-1);
      int iy0=min(max((int)fy,0),res-1);
      int iz0=min(max((int)fz,0),res-1);
      int ix1=min(ix0+1,res-1), iy1=min(iy0+1,res-1), iz1=min(iz0+1,res-1);
      const bool dense = (lvl < 3);
      unsigned X0,X1,Y0,Y1,Z0,Z1;
      if (dense){
        X0=(unsigned)ix0;            X1=(unsigned)ix1;
        Y0=(unsigned)(res*iy0);      Y1=(unsigned)(res*iy1);
        Z0=(unsigned)(res*res*iz0);  Z1=(unsigned)(res*res*iz1);
      } else {
        X0=(unsigned)ix0;                 X1=(unsigned)ix1;
        Y0=(unsigned)iy0*2654435761u;     Y1=(unsigned)iy1*2654435761u;
        Z0=(unsigned)iz0*805459861u;      Z1=(unsigned)iz1*805459861u;
      }
      const float wx0=1.f-wx, wy0=1.f-wy, wz0=1.f-wz;
      float f0=0.f, f1=0.f;
      const float2* tl = (const float2*)tab + (lvl<<14);
#pragma unroll
      for (int c = 0; c < 8; ++c){
        unsigned xc = (c&1)?X1:X0;
        unsigned yc = (c&2)?Y1:Y0;
        unsigned zc = (c&4)?Z1:Z0;
        unsigned idx = dense ? (xc+yc+zc) : ((xc^yc^zc)&16383u);
        float2 tv = tl[idx];
        float wc = ((c&1)?wx:wx0) * ((c&2)?wy:wy0) * ((c&4)?wz:wz0);
        f0 += wc*tv.x;
        f1 += wc*tv.y;
      }
      bfrag[2*d]   = (__bf16)f0;
      bfrag[2*d+1] = (__bf16)f1;
    }
    MLP_BODY(bfrag, gp)
  }
}

extern "C" void kernel_launch(void* const* d_in, const int* in_sizes, int n_in,
                              void* d_out, int out_size, void* d_ws, size_t ws_size,
                              hipStream_t stream) {
  (void)n_in; (void)out_size;
  const int nB = in_sizes[0] / 3;
  const float* xin = (const float*)d_in[0];
  const float* tab = (const float*)d_in[1];
  const float *w1=(const float*)d_in[2],  *b1=(const float*)d_in[3];
  const float *w2=(const float*)d_in[4],  *b2=(const float*)d_in[5];
  const float *w3=(const float*)d_in[6],  *b3=(const float*)d_in[7];
  const float *cw1=(const float*)d_in[8], *cb1=(const float*)d_in[9];
  const float *cw2=(const float*)d_in[10],*cb2=(const float*)d_in[11];
  const float *cw3=(const float*)d_in[12],*cb3=(const float*)d_in[13];
  const float *cw4=(const float*)d_in[14],*cb4=(const float*)d_in[15];
  float* out = (float*)d_out;

  const size_t need  = (size_t)nB * 16u * 4u;        // feat[level][point]
  const size_t needp = need + 16u * 16384u * 4u;     // + packed tables (1 MB)
  if (ws_size >= needp){
    unsigned int* feat = (unsigned int*)d_ws;
    unsigned int* tabp = feat + (size_t)nB * 16u;
    tab_pack<<<dim3(512), dim3(512), 0, stream>>>(tab, tabp);
    dim3 ga((nB + CH - 1) / CH, 16);
    hash_phase<<<ga, dim3(512), 0, stream>>>(xin, tabp, feat, nB);
    const int blocks = (nB + PTS_PER_BLOCK - 1) / PTS_PER_BLOCK;
    mlp32_phase<<<dim3(blocks), dim3(BLOCK), 0, stream>>>(
        feat, w1,b1,w2,b2,w3,b3,
        cw1,cb1,cw2,cb2,cw3,cb3,cw4,cb4, out, nB);
  } else if (ws_size >= need){
    dim3 ga((nB + CH - 1) / CH, 16);
    hash_phase_f32<<<ga, dim3(512), 0, stream>>>(xin, tab, (unsigned int*)d_ws, nB);
    const int blocks = (nB + PTS_PER_BLOCK - 1) / PTS_PER_BLOCK;
    mlp32_phase<<<dim3(blocks), dim3(BLOCK), 0, stream>>>(
        (const unsigned int*)d_ws, w1,b1,w2,b2,w3,b3,
        cw1,cb1,cw2,cb2,cw3,cb3,cw4,cb4, out, nB);
  } else {
    const int blocks = (nB + BLOCK - 1) / BLOCK;
    nerf_fused<<<dim3(blocks), dim3(BLOCK), 0, stream>>>(
        xin, tab, w1,b1,w2,b2,w3,b3,
        cw1,cb1,cw2,cb2,cw3,cb3,cw4,cb4, out, nB);
  }
}

// Round 8
// 167.735 us; speedup vs baseline: 1.0709x; 1.0709x over previous
//
#include <hip/hip_runtime.h>

typedef __bf16 bf8 __attribute__((ext_vector_type(8)));
typedef float f4 __attribute__((ext_vector_type(4)));
typedef float f32x16 __attribute__((ext_vector_type(16)));
typedef unsigned short us4 __attribute__((ext_vector_type(4)));
typedef unsigned int u32x4 __attribute__((ext_vector_type(4)));

#define MFMA16(a,b,c) __builtin_amdgcn_mfma_f32_16x16x32_bf16((a),(b),(c),0,0,0)
#define MFMA32(a,b,c) __builtin_amdgcn_mfma_f32_32x32x16_bf16((a),(b),(c),0,0,0)

#define BLOCK 512
#define NWAVE 8

__device__ __forceinline__ unsigned short f2bfu(float f){
  __bf16 h = (__bf16)f;
  union { __bf16 b; unsigned short u; } v; v.b = h; return v.u;
}
__device__ __forceinline__ float ubfu(unsigned int u16){
  union { unsigned int i; float f; } v; v.i = u16 << 16; return v.f;
}

// Wave-local LDS fence (fused fallback kernel only).
__device__ __forceinline__ void wfence(){
  asm volatile("s_waitcnt lgkmcnt(0)" ::: "memory");
}

// Scheduler cage (validated r5): stops cross-layer hoisting of loop-invariant
// weight ds_reads -> elastic register demand -> spill (r3/r4: 1.2-1.7 GB).
// r7 lesson: persistent frags + manual prefetch COST occupancy (-1 wave/SIMD)
// and regressed 69->79 us; r5's 3-waves/SIMD overlap already hides the
// per-layer lgkmcnt stall. Keep the plain r5 region structure.
#define SBAR() __builtin_amdgcn_sched_barrier(0)

// ---------------- old 16x16 layout (fused fallback kernel only) ------------
#define OFF_W1   0
#define OFF_W2   2048
#define OFF_W3   6144
#define OFF_CW1  7168
#define OFF_CW2  8192
#define OFF_CW3  12288
#define OFF_CW4  16384
#define OFF_ACT  17408
#define ACT_STRIDE 72
#define SMEM_US  (17408 + NWAVE*16*ACT_STRIDE)

#define BO_B1  0
#define BO_B2  64
#define BO_B3  128
#define BO_CB1 144
#define BO_CB2 208
#define BO_CB3 272
#define BO_CB4 336

template<int FIN,int FOUT,int KS,int MT>
__device__ __forceinline__ void stage_w(const float* w, unsigned short* dst){
  const int total = KS*MT*512;
  for (int e = threadIdx.x; e < total; e += BLOCK){
    int chunk = e >> 9;
    int s = chunk / MT, t = chunk % MT;
    int le = e & 511;
    int lane = le >> 3, j = le & 7;
    int q = lane >> 4, m = lane & 15;
    int i = s*32 + q*8 + j;
    int o = t*16 + m;
    dst[e] = (i < FIN && o < FOUT) ? f2bfu(w[i*FOUT + o]) : (unsigned short)0;
  }
}

__device__ __forceinline__ void stage_cw1(const float* w, unsigned short* dst){
  for (int e = threadIdx.x; e < 1024; e += BLOCK){
    int t = e >> 8;
    int le = e & 255;
    int lane = le >> 3, j = e & 7;
    int q = lane >> 4, m = lane & 15;
    dst[e] = f2bfu(w[(q*8+j)*64 + t*16 + m]);
  }
}

__device__ __forceinline__ void layer64(const unsigned short* wlds, const unsigned short* bias,
                                        unsigned short* act, int lane, bool relu){
  const int q = lane >> 4, m = lane & 15;
  bf8 b0 = *(const bf8*)(act + m*ACT_STRIDE + q*8);
  bf8 b1 = *(const bf8*)(act + m*ACT_STRIDE + 32 + q*8);
  f4 acc[4];
#pragma unroll
  for (int t = 0; t < 4; ++t){
    f4 c = {0.f,0.f,0.f,0.f};
    c = MFMA16(*(const bf8*)(wlds + ((0*4+t)*64+lane)*8), b0, c);
    c = MFMA16(*(const bf8*)(wlds + ((1*4+t)*64+lane)*8), b1, c);
    acc[t] = c;
  }
#pragma unroll
  for (int t = 0; t < 4; ++t){
    us4 bb = *(const us4*)(bias + t*16 + q*4);
    us4 pk;
#pragma unroll
    for (int r = 0; r < 4; ++r){
      float v = acc[t][r] + ubfu(bb[r]);
      if (relu) v = fmaxf(v, 0.f);
      pk[r] = f2bfu(v);
    }
    *(us4*)(act + m*ACT_STRIDE + t*16 + q*4) = pk;
  }
}

#define STAGE_ALL_WEIGHTS()                                                  \
  stage_w<32,64,1,4>(w1,  smem+OFF_W1);                                      \
  stage_w<64,64,2,4>(w2,  smem+OFF_W2);                                      \
  stage_w<64,16,2,1>(w3,  smem+OFF_W3);                                      \
  stage_cw1(cw1, smem+OFF_CW1);                                              \
  stage_w<64,64,2,4>(cw2, smem+OFF_CW2);                                     \
  stage_w<64,64,2,4>(cw3, smem+OFF_CW3);                                     \
  stage_w<64, 3,2,1>(cw4, smem+OFF_CW4);                                     \
  {                                                                          \
    int t = threadIdx.x;                                                     \
    if (t < 64){                                                             \
      sbias[BO_B1 +t] = f2bfu(b1[t]);                                        \
      sbias[BO_B2 +t] = f2bfu(b2[t]);                                        \
      sbias[BO_CB1+t] = f2bfu(cb1[t]);                                       \
      sbias[BO_CB2+t] = f2bfu(cb2[t]);                                       \
      sbias[BO_CB3+t] = f2bfu(cb3[t]);                                       \
    }                                                                        \
    if (t < 16) sbias[BO_B3+t] = f2bfu(b3[t]);                               \
    if (t < 3)  sbias[BO_CB4+t] = f2bfu(cb4[t]);                             \
  }

#define MLP_BODY(bfrag, gp)                                                  \
    {                                                                        \
      f4 acc[4];                                                             \
      _Pragma("unroll")                                                      \
      for (int t = 0; t < 4; ++t){                                           \
        f4 c = {0.f,0.f,0.f,0.f};                                            \
        acc[t] = MFMA16(*(const bf8*)(smem + OFF_W1 + (t*64+lane)*8), bfrag, c);\
      }                                                                      \
      _Pragma("unroll")                                                      \
      for (int t = 0; t < 4; ++t){                                           \
        us4 bb = *(const us4*)(sbias + BO_B1 + t*16 + q*4);                  \
        us4 pk;                                                              \
        _Pragma("unroll")                                                    \
        for (int r = 0; r < 4; ++r){                                         \
          float v = fmaxf(acc[t][r] + ubfu(bb[r]), 0.f);                     \
          pk[r] = f2bfu(v);                                                  \
        }                                                                    \
        *(us4*)(act + m*ACT_STRIDE + t*16 + q*4) = pk;                       \
      }                                                                      \
    }                                                                        \
    wfence();                                                                \
    layer64(smem+OFF_W2, sbias+BO_B2, act, lane, true);                      \
    wfence();                                                                \
    {                                                                        \
      bf8 b0 = *(const bf8*)(act + m*ACT_STRIDE + q*8);                      \
      bf8 b1 = *(const bf8*)(act + m*ACT_STRIDE + 32 + q*8);                 \
      f4 c = {0.f,0.f,0.f,0.f};                                              \
      c = MFMA16(*(const bf8*)(smem + OFF_W3 + lane*8), b0, c);              \
      c = MFMA16(*(const bf8*)(smem + OFF_W3 + (64+lane)*8), b1, c);         \
      us4 bb = *(const us4*)(sbias + BO_B3 + q*4);                           \
      us4 pk;                                                                \
      float d0 = 0.f;                                                        \
      _Pragma("unroll")                                                      \
      for (int r = 0; r < 4; ++r){                                           \
        float v = c[r] + ubfu(bb[r]);                                        \
        if (r == 0) d0 = v;                                                  \
        pk[r] = f2bfu(v);                                                    \
      }                                                                      \
      if (q == 0 && gp < nB) out[gp] = expf(d0);                             \
      *(us4*)(act + m*ACT_STRIDE + q*4) = pk;                                \
    }                                                                        \
    wfence();                                                                \
    {                                                                        \
      bf8 bc, aw[4];                                                         \
      if (q < 2){                                                            \
        bc = *(const bf8*)(act + m*ACT_STRIDE + q*8);                        \
        _Pragma("unroll")                                                    \
        for (int t = 0; t < 4; ++t)                                          \
          aw[t] = *(const bf8*)(smem + OFF_CW1 + (t*32+lane)*8);             \
      } else {                                                               \
        _Pragma("unroll")                                                    \
        for (int j = 0; j < 8; ++j) bc[j] = (__bf16)0.f;                     \
        _Pragma("unroll")                                                    \
        for (int t = 0; t < 4; ++t) aw[t] = bc;                              \
      }                                                                      \
      f4 acc[4];                                                             \
      _Pragma("unroll")                                                      \
      for (int t = 0; t < 4; ++t){                                           \
        f4 c = {0.f,0.f,0.f,0.f};                                            \
        acc[t] = MFMA16(aw[t], bc, c);                                       \
      }                                                                      \
      _Pragma("unroll")                                                      \
      for (int t = 0; t < 4; ++t){                                           \
        us4 bb = *(const us4*)(sbias + BO_CB1 + t*16 + q*4);                 \
        us4 pk;                                                              \
        _Pragma("unroll")                                                    \
        for (int r = 0; r < 4; ++r){                                         \
          float v = fmaxf(acc[t][r] + ubfu(bb[r]), 0.f);                     \
          pk[r] = f2bfu(v);                                                  \
        }                                                                    \
        *(us4*)(act + m*ACT_STRIDE + t*16 + q*4) = pk;                       \
      }                                                                      \
    }                                                                        \
    wfence();                                                                \
    layer64(smem+OFF_CW2, sbias+BO_CB2, act, lane, true);                    \
    wfence();                                                                \
    layer64(smem+OFF_CW3, sbias+BO_CB3, act, lane, true);                    \
    wfence();                                                                \
    {                                                                        \
      bf8 b0 = *(const bf8*)(act + m*ACT_STRIDE + q*8);                      \
      bf8 b1 = *(const bf8*)(act + m*ACT_STRIDE + 32 + q*8);                 \
      f4 c = {0.f,0.f,0.f,0.f};                                              \
      c = MFMA16(*(const bf8*)(smem + OFF_CW4 + lane*8), b0, c);             \
      c = MFMA16(*(const bf8*)(smem + OFF_CW4 + (64+lane)*8), b1, c);        \
      if (q == 0 && gp < nB){                                                \
        _Pragma("unroll")                                                    \
        for (int r = 0; r < 3; ++r){                                         \
          float v = c[r] + ubfu(sbias[BO_CB4 + r]);                          \
          out[nB + gp*3 + r] = 1.f/(1.f + expf(-v));                         \
        }                                                                    \
      }                                                                      \
    }                                                                        \
    wfence();

// ---------------------------------------------------------------------------
// Table prepack: tables f32x2 -> packed bf16x2 uint, once.
// ---------------------------------------------------------------------------
__global__ __launch_bounds__(512) void tab_pack(
    const float* __restrict__ tab, unsigned int* __restrict__ tp)
{
  int e = blockIdx.x*512 + threadIdx.x;     // grid 512 -> 262144 entries
  float2 v = ((const float2*)tab)[e];
  tp[e] = ((unsigned)f2bfu(v.y) << 16) | (unsigned)f2bfu(v.x);
}

// ---------------------------------------------------------------------------
// Phase A: per-level hash encode, full table in LDS, 2-pt unroll.
// ---------------------------------------------------------------------------
#define CH 16384

#define HASH_BODY_COMMON                                                     \
  const int res = sres[lvl];                                                 \
  const float sc = 0.5f*(float)(res-1);                                      \
  const bool dense = (lvl < 3);                                              \
  unsigned int* fout = feat + (size_t)lvl * (size_t)nB;                      \
  auto body = [&](int p){                                                    \
    const float px = xin[p*3+0], py = xin[p*3+1], pz = xin[p*3+2];           \
    const float xs=(px+1.f)*sc, ys=(py+1.f)*sc, zs=(pz+1.f)*sc;              \
    const float fx=floorf(xs), fy=floorf(ys), fz=floorf(zs);                 \
    const float wx=xs-fx, wy=ys-fy, wz=zs-fz;                                \
    int ix0=min(max((int)fx,0),res-1);                                       \
    int iy0=min(max((int)fy,0),res-1);                                       \
    int iz0=min(max((int)fz,0),res-1);                                       \
    int ix1=min(ix0+1,res-1), iy1=min(iy0+1,res-1), iz1=min(iz0+1,res-1);    \
    unsigned X0,X1,Y0,Y1,Z0,Z1;                                              \
    if (dense){                                                              \
      X0=(unsigned)ix0;            X1=(unsigned)ix1;                         \
      Y0=(unsigned)(res*iy0);      Y1=(unsigned)(res*iy1);                   \
      Z0=(unsigned)(res*res*iz0);  Z1=(unsigned)(res*res*iz1);               \
    } else {                                                                 \
      X0=(unsigned)ix0;                 X1=(unsigned)ix1;                    \
      Y0=(unsigned)iy0*2654435761u;     Y1=(unsigned)iy1*2654435761u;        \
      Z0=(unsigned)iz0*805459861u;      Z1=(unsigned)iz1*805459861u;         \
    }                                                                        \
    const float wx0=1.f-wx, wy0=1.f-wy, wz0=1.f-wz;                          \
    float f0=0.f, f1=0.f;                                                    \
    _Pragma("unroll")                                                        \
    for (int c = 0; c < 8; ++c){                                             \
      unsigned xc = (c&1)?X1:X0;                                             \
      unsigned yc = (c&2)?Y1:Y0;                                             \
      unsigned zc = (c&4)?Z1:Z0;                                             \
      unsigned idx = dense ? (xc+yc+zc) : ((xc^yc^zc)&16383u);               \
      unsigned tv = stab[idx];                                               \
      float wc = ((c&1)?wx:wx0) * ((c&2)?wy:wy0) * ((c&4)?wz:wz0);           \
      f0 += wc*ubfu(tv << 16);                                               \
      f1 += wc*ubfu(tv & 0xffff0000u);                                       \
    }                                                                        \
    fout[p] = ((unsigned)f2bfu(f1) << 16) | (unsigned)f2bfu(f0);             \
  };                                                                         \
  int pend = (blockIdx.x + 1) * CH; if (pend > nB) pend = nB;                \
  int p = blockIdx.x*CH + threadIdx.x;                                       \
  for (; p + 512 < pend; p += 1024){ body(p); body(p + 512); }               \
  if (p < pend) body(p);

__global__ __launch_bounds__(512) void hash_phase(
    const float* __restrict__ xin, const unsigned int* __restrict__ tabp,
    unsigned int* __restrict__ feat, int nB)
{
  __shared__ __align__(16) unsigned int stab[16384];
  __shared__ int sres[16];
  const int lvl = blockIdx.y;
  {
    const u32x4* t4 = (const u32x4*)(tabp + (lvl<<14));
    u32x4* s4 = (u32x4*)stab;
    for (int e = threadIdx.x; e < 4096; e += 512) s4[e] = t4[e];
    if (threadIdx.x < 16){
      const int R[16] = {16,20,25,32,40,50,64,80,101,128,161,203,256,322,406,512};
      sres[threadIdx.x] = R[threadIdx.x];
    }
  }
  __syncthreads();
  HASH_BODY_COMMON
}

// fallback variant: stage from f32 tables directly (ws fits feat only)
__global__ __launch_bounds__(512) void hash_phase_f32(
    const float* __restrict__ xin, const float* __restrict__ tab,
    unsigned int* __restrict__ feat, int nB)
{
  __shared__ __align__(16) unsigned int stab[16384];
  __shared__ int sres[16];
  const int lvl = blockIdx.y;
  {
    const float2* t2 = (const float2*)tab + (lvl<<14);
    for (int e = threadIdx.x; e < 16384; e += 512){
      float2 v = t2[e];
      stab[e] = ((unsigned)f2bfu(v.y) << 16) | (unsigned)f2bfu(v.x);
    }
    if (threadIdx.x < 16){
      const int R[16] = {16,20,25,32,40,50,64,80,101,128,161,203,256,322,406,512};
      sres[threadIdx.x] = R[threadIdx.x];
    }
  }
  __syncthreads();
  HASH_BODY_COMMON
}

// ===========================================================================
// Phase B v9 = r5 structure (best: 69 us, VGPR 48, occ 37%) + permuted-bias
// LDS. bias16 was 4 strided f4 ds_reads + 16 v_movs per call, 10 calls/iter
// (~80 movs + 40 reads on every layer's critical path; VALUBusy 55% was the
// top pipe). Biases now stored PERMUTED so the C-init is one contiguous
// f32x16 broadcast load: dst[half*32 + h*16 + 4g + j] = bias[32*half+8g+4h+j].
// Address uniform within each 32-lane half -> conflict-free broadcast.
// ===========================================================================

// 32x32 A-frag staging layout (ushort offsets)
#define W32_W1   0        // MT2 KT2: 2048
#define W32_W2   2048     // MT2 KT4: 4096
#define W32_W3   6144     // MT1 KT4: 2048 (FOUT=16 padded to 32)
#define W32_CW1  8192     // MT2 KT1: 1024
#define W32_CW2  9216     // MT2 KT4: 4096
#define W32_CW3  13312    // MT2 KT4: 4096
#define W32_CW4  17408    // MT1 KT4: 2048 (FOUT=3 padded)
#define W32_TOT  19456

// f32 bias offsets (permuted layout)
#define SB_B1  0
#define SB_B2  64
#define SB_CB1 128
#define SB_CB2 192
#define SB_CB3 256
#define SB_B3  320   // 32 entries (16 real + 16 zero), single half
#define SB_CB4 352   // 32 entries (3 real + zeros), single half

// A-frag stager: frag = mt*KT+kt; lane l elem j -> W[kt*16+(l>>5)*8+j][mt*32+(l&31)]
template<int FIN,int FOUT,int MT,int KT>
__device__ __forceinline__ void stage32(const float* w, unsigned short* dst){
  const int total = MT*KT*512;
  for (int e = threadIdx.x; e < total; e += BLOCK){
    int frag = e >> 9;
    int mt = frag / KT, kt = frag % KT;
    int l  = (e >> 3) & 63, j = e & 7;
    int i  = kt*16 + ((l >> 5) << 3) + j;
    int o  = mt*32 + (l & 31);
    dst[e] = (i < FIN && o < FOUT) ? f2bfu(w[i*FOUT + o]) : (unsigned short)0;
  }
}

// permuted-bias dst index for source row t (0..63):
// half=t>>5, rw=t&31: g=rw>>3, hh=(rw>>2)&1, j=rw&3 -> half*32 + hh*16 + 4g + j
__device__ __forceinline__ int bperm(int t){
  int half = t >> 5, rw = t & 31;
  return half*32 + ((rw >> 2) & 1)*16 + (rw >> 3)*4 + (rw & 3);
}

__device__ __forceinline__ unsigned pk2(float x, float y){
  typedef __bf16 bf2v __attribute__((ext_vector_type(2)));
  union { bf2v b; unsigned u; } v;
  v.b[0] = (__bf16)x; v.b[1] = (__bf16)y;
  return v.u;
}

__device__ __forceinline__ bf8 mkbf8(unsigned d0, unsigned d1, unsigned d2, unsigned d3){
  union { u32x4 u; bf8 b; } v;
  v.u[0] = d0; v.u[1] = d1; v.u[2] = d2; v.u[3] = d3;
  return v.b;
}

// Exchange 32-lane halves: x = {a_lo, b_lo}, y = {a_hi, b_hi}.
__device__ __forceinline__ void swap_half(unsigned a, unsigned b, unsigned& x, unsigned& y){
#if __has_builtin(__builtin_amdgcn_permlane32_swap)
  auto r = __builtin_amdgcn_permlane32_swap(a, b, false, false);
  x = r[0]; y = r[1];
#else
  unsigned sa = (unsigned)__shfl_xor((int)a, 32, 64);
  unsigned sb = (unsigned)__shfl_xor((int)b, 32, 64);
  bool lo = (threadIdx.x & 32) == 0;
  x = lo ? a : sb;
  y = lo ? sa : b;
#endif
}

// bias C-init: one contiguous f32x16 broadcast load from the permuted array.
// half selects rows 0..31 / 32..63 of the layer; h is the lane's half-group.
__device__ __forceinline__ f32x16 bias16(const float* sbp, int half, int h){
  return *(const f32x16*)(sbp + half*32 + h*16);
}

// 64-wide layer output (a0=rows 0..31, a1=rows 32..63) -> relu -> 4 B-frags
__device__ __forceinline__ void trans2(const f32x16 a0, const f32x16 a1, bf8* B){
  unsigned p0[8], p1[8];
#pragma unroll
  for (int p = 0; p < 8; ++p){
    p0[p] = pk2(fmaxf(a0[2*p], 0.f), fmaxf(a0[2*p+1], 0.f));
    p1[p] = pk2(fmaxf(a1[2*p], 0.f), fmaxf(a1[2*p+1], 0.f));
  }
#pragma unroll
  for (int o = 0; o < 2; ++o){
    unsigned x0,y0,x1,y1;
    swap_half(p0[4*o+0], p0[4*o+2], x0, y0);
    swap_half(p0[4*o+1], p0[4*o+3], x1, y1);
    B[o] = mkbf8(x0, x1, y0, y1);
    swap_half(p1[4*o+0], p1[4*o+2], x0, y0);
    swap_half(p1[4*o+1], p1[4*o+3], x1, y1);
    B[2+o] = mkbf8(x0, x1, y0, y1);
  }
}

#define PTS_PER_BLOCK 1024
#define M_ITERS 4

__global__ __launch_bounds__(BLOCK, 2) void mlp32_phase(
    const unsigned int* __restrict__ feat,
    const float* __restrict__ w1,  const float* __restrict__ b1,
    const float* __restrict__ w2,  const float* __restrict__ b2,
    const float* __restrict__ w3,  const float* __restrict__ b3,
    const float* __restrict__ cw1, const float* __restrict__ cb1,
    const float* __restrict__ cw2, const float* __restrict__ cb2,
    const float* __restrict__ cw3, const float* __restrict__ cb3,
    const float* __restrict__ cw4, const float* __restrict__ cb4,
    float* __restrict__ out, int nB)
{
  __shared__ __align__(16) unsigned short sw[W32_TOT];
  __shared__ __align__(64) float sbf[384];
  stage32<32,64,2,2>(w1,  sw+W32_W1);
  stage32<64,64,2,4>(w2,  sw+W32_W2);
  stage32<64,16,1,4>(w3,  sw+W32_W3);
  stage32<16,64,2,1>(cw1, sw+W32_CW1);
  stage32<64,64,2,4>(cw2, sw+W32_CW2);
  stage32<64,64,2,4>(cw3, sw+W32_CW3);
  stage32<64, 3,1,4>(cw4, sw+W32_CW4);
  {
    int t = threadIdx.x;
    if (t < 64){
      int d = bperm(t);
      sbf[SB_B1 +d] = b1[t];
      sbf[SB_B2 +d] = b2[t];
      sbf[SB_CB1+d] = cb1[t];
      sbf[SB_CB2+d] = cb2[t];
      sbf[SB_CB3+d] = cb3[t];
    }
    if (t >= 64 && t < 96){
      int s = t - 64;                 // source row 0..31
      sbf[SB_B3 + bperm(s)] = (s < 16) ? b3[s] : 0.f;
    }
    if (t >= 96 && t < 128){
      int s = t - 96;
      sbf[SB_CB4 + bperm(s)] = (s < 3) ? cb4[s] : 0.f;
    }
  }
  __syncthreads();

  const int l  = threadIdx.x & 63, wv = threadIdx.x >> 6;
  const int h  = l >> 5, n = l & 31, h4 = h << 2;
  const int base0 = blockIdx.x * PTS_PER_BLOCK + wv*32 + n;

#define FR(off, frag) (*(const bf8*)(sw + (off) + ((frag) << 9) + (l << 3)))
#define LOADF(d0, d1, g) {                                                   \
    int gg = min((g), nB-1);                                                 \
    _Pragma("unroll")                                                        \
    for (int d = 0; d < 4; ++d){                                             \
      d0[d] = feat[(size_t)(h4 + d)*(size_t)nB + gg];                        \
      d1[d] = feat[(size_t)(8 + h4 + d)*(size_t)nB + gg];                    \
    } }

  u32x4 f0, f1, nf0, nf1;
  LOADF(f0, f1, base0)

  for (int it = 0; it < M_ITERS; ++it){
    const int gp = base0 + it*256;
    bf8 B[4];
    B[0] = mkbf8(f0[0], f0[1], f0[2], f0[3]);
    B[1] = mkbf8(f1[0], f1[1], f1[2], f1[3]);
    SBAR();

    // L1: 32 -> 64, relu
    f32x16 a0 = bias16(sbf + SB_B1, 0, h);
    f32x16 a1 = bias16(sbf + SB_B1, 1, h);
    a0 = MFMA32(FR(W32_W1,0), B[0], a0);
    a0 = MFMA32(FR(W32_W1,1), B[1], a0);
    a1 = MFMA32(FR(W32_W1,2), B[0], a1);
    a1 = MFMA32(FR(W32_W1,3), B[1], a1);
    SBAR();

    if (it + 1 < M_ITERS){ LOADF(nf0, nf1, gp + 256) }
    SBAR();

    trans2(a0, a1, B);
    SBAR();

    // L2: 64 -> 64, relu
    a0 = bias16(sbf + SB_B2, 0, h);
    a1 = bias16(sbf + SB_B2, 1, h);
#pragma unroll
    for (int kt = 0; kt < 4; ++kt){
      a0 = MFMA32(FR(W32_W2, kt),   B[kt], a0);
      a1 = MFMA32(FR(W32_W2, 4+kt), B[kt], a1);
    }
    SBAR();
    trans2(a0, a1, B);
    SBAR();

    // L3: 64 -> 16 (padded to 32, no relu); sigma = exp(d0)
    f32x16 ad = bias16(sbf + SB_B3, 0, h);
#pragma unroll
    for (int kt = 0; kt < 4; ++kt) ad = MFMA32(FR(W32_W3, kt), B[kt], ad);
    SBAR();
    if (h == 0 && gp < nB) out[gp] = expf(ad[0]);
    {
      unsigned q0 = pk2(ad[0], ad[1]);
      unsigned q1 = pk2(ad[2], ad[3]);
      unsigned q2 = pk2(ad[4], ad[5]);
      unsigned q3 = pk2(ad[6], ad[7]);
      unsigned x0,y0,x1,y1;
      swap_half(q0, q2, x0, y0);
      swap_half(q1, q3, x1, y1);
      B[0] = mkbf8(x0, x1, y0, y1);
    }
    SBAR();

    // C1: 16 -> 64, relu
    a0 = bias16(sbf + SB_CB1, 0, h);
    a1 = bias16(sbf + SB_CB1, 1, h);
    a0 = MFMA32(FR(W32_CW1,0), B[0], a0);
    a1 = MFMA32(FR(W32_CW1,1), B[0], a1);
    SBAR();
    trans2(a0, a1, B);
    SBAR();

    // C2: 64 -> 64, relu
    a0 = bias16(sbf + SB_CB2, 0, h);
    a1 = bias16(sbf + SB_CB2, 1, h);
#pragma unroll
    for (int kt = 0; kt < 4; ++kt){
      a0 = MFMA32(FR(W32_CW2, kt),   B[kt], a0);
      a1 = MFMA32(FR(W32_CW2, 4+kt), B[kt], a1);
    }
    SBAR();
    trans2(a0, a1, B);
    SBAR();

    // C3: 64 -> 64, relu
    a0 = bias16(sbf + SB_CB3, 0, h);
    a1 = bias16(sbf + SB_CB3, 1, h);
#pragma unroll
    for (int kt = 0; kt < 4; ++kt){
      a0 = MFMA32(FR(W32_CW3, kt),   B[kt], a0);
      a1 = MFMA32(FR(W32_CW3, 4+kt), B[kt], a1);
    }
    SBAR();
    trans2(a0, a1, B);
    SBAR();

    // C4: 64 -> 3, sigmoid
    f32x16 ac = bias16(sbf + SB_CB4, 0, h);
#pragma unroll
    for (int kt = 0; kt < 4; ++kt) ac = MFMA32(FR(W32_CW4, kt), B[kt], ac);
    SBAR();
    if (h == 0 && gp < nB){
      out[nB + gp*3 + 0] = 1.f/(1.f + expf(-ac[0]));
      out[nB + gp*3 + 1] = 1.f/(1.f + expf(-ac[1]));
      out[nB + gp*3 + 2] = 1.f/(1.f + expf(-ac[2]));
    }
    SBAR();

    if (it + 1 < M_ITERS){ f0 = nf0; f1 = nf1; }
  }
#undef FR
#undef LOADF
}

// ---------------------------------------------------------------------------
// Fallback: fused kernel (used only if workspace too small).
// ---------------------------------------------------------------------------
__global__ __launch_bounds__(BLOCK) void nerf_fused(
    const float* __restrict__ xin, const float* __restrict__ tab,
    const float* __restrict__ w1,  const float* __restrict__ b1,
    const float* __restrict__ w2,  const float* __restrict__ b2,
    const float* __restrict__ w3,  const float* __restrict__ b3,
    const float* __restrict__ cw1, const float* __restrict__ cb1,
    const float* __restrict__ cw2, const float* __restrict__ cb2,
    const float* __restrict__ cw3, const float* __restrict__ cb3,
    const float* __restrict__ cw4, const float* __restrict__ cb4,
    float* __restrict__ out, int nB)
{
  __shared__ __align__(16) unsigned short smem[SMEM_US];
  __shared__ __align__(16) unsigned short sbias[344];
  __shared__ int sres[16];
  STAGE_ALL_WEIGHTS();
  if (threadIdx.x < 16){
    const int R[16] = {16,20,25,32,40,50,64,80,101,128,161,203,256,322,406,512};
    sres[threadIdx.x] = R[threadIdx.x];
  }
  __syncthreads();

  const int lane = threadIdx.x & 63, wv = threadIdx.x >> 6;
  const int q = lane >> 4, m = lane & 15;
  unsigned short* act = smem + OFF_ACT + wv*16*ACT_STRIDE;

  int res_[4];
#pragma unroll
  for (int d = 0; d < 4; ++d) res_[d] = sres[4*q + d];

  for (int it = 0; it < 4; ++it){
    const int gp  = blockIdx.x*BLOCK + wv*64 + it*16 + m;
    const int gpl = min(gp, nB-1);
    const float px = xin[gpl*3+0];
    const float py = xin[gpl*3+1];
    const float pz = xin[gpl*3+2];

    bf8 bfrag;
#pragma unroll
    for (int d = 0; d < 4; ++d){
      const int lvl = 4*q + d;
      const int res = res_[d];
      const float sc = 0.5f*(float)(res-1);
      const float xs=(px+1.f)*sc, ys=(py+1.f)*sc, zs=(pz+1.f)*sc;
      const float fx=floorf(xs), fy=floorf(ys), fz=floorf(zs);
      const float wx=xs-fx, wy=ys-fy, wz=zs-fz;
      int ix0=min(max((int)fx,0),res-1);
      int iy0=min(max((int)fy,0),res-1);
      int iz0=min(max((int)fz,0),res-1);
      int ix1=min(ix0+1,res-1), iy1=min(iy0+1,res-1), iz1=min(iz0+1,res-1);
      const bool dense = (lvl < 3);
      unsigned X0,X1,Y0,Y1,Z0,Z1;
      if (dense){
        X0=(unsigned)ix0;            X1=(unsigned)ix1;
        Y0=(unsigned)(res*iy0);      Y1=(unsigned)(res*iy1);
        Z0=(unsigned)(res*res*iz0);  Z1=(unsigned)(res*res*iz1);
      } else {
        X0=(unsigned)ix0;                 X1=(unsigned)ix1;
        Y0=(unsigned)iy0*2654435761u;     Y1=(unsigned)iy1*2654435761u;
        Z0=(unsigned)iz0*805459861u;      Z1=(unsigned)iz1*805459861u;
      }
      const float wx0=1.f-wx, wy0=1.f-wy, wz0=1.f-wz;
      float f0=0.f, f1=0.f;
      const float2* tl = (const float2*)tab + (lvl<<14);
#pragma unroll
      for (int c = 0; c < 8; ++c){
        unsigned xc = (c&1)?X1:X0;
        unsigned yc = (c&2)?Y1:Y0;
        unsigned zc = (c&4)?Z1:Z0;
        unsigned idx = dense ? (xc+yc+zc) : ((xc^yc^zc)&16383u);
        float2 tv = tl[idx];
        float wc = ((c&1)?wx:wx0) * ((c&2)?wy:wy0) * ((c&4)?wz:wz0);
        f0 += wc*tv.x;
        f1 += wc*tv.y;
      }
      bfrag[2*d]   = (__bf16)f0;
      bfrag[2*d+1] = (__bf16)f1;
    }
    MLP_BODY(bfrag, gp)
  }
}

extern "C" void kernel_launch(void* const* d_in, const int* in_sizes, int n_in,
                              void* d_out, int out_size, void* d_ws, size_t ws_size,
                              hipStream_t stream) {
  (void)n_in; (void)out_size;
  const int nB = in_sizes[0] / 3;
  const float* xin = (const float*)d_in[0];
  const float* tab = (const float*)d_in[1];
  const float *w1=(const float*)d_in[2],  *b1=(const float*)d_in[3];
  const float *w2=(const float*)d_in[4],  *b2=(const float*)d_in[5];
  const float *w3=(const float*)d_in[6],  *b3=(const float*)d_in[7];
  const float *cw1=(const float*)d_in[8], *cb1=(const float*)d_in[9];
  const float *cw2=(const float*)d_in[10],*cb2=(const float*)d_in[11];
  const float *cw3=(const float*)d_in[12],*cb3=(const float*)d_in[13];
  const float *cw4=(const float*)d_in[14],*cb4=(const float*)d_in[15];
  float* out = (float*)d_out;

  const size_t need  = (size_t)nB * 16u * 4u;        // feat[level][point]
  const size_t needp = need + 16u * 16384u * 4u;     // + packed tables (1 MB)
  if (ws_size >= needp){
    unsigned int* feat = (unsigned int*)d_ws;
    unsigned int* tabp = feat + (size_t)nB * 16u;
    tab_pack<<<dim3(512), dim3(512), 0, stream>>>(tab, tabp);
    dim3 ga((nB + CH - 1) / CH, 16);
    hash_phase<<<ga, dim3(512), 0, stream>>>(xin, tabp, feat, nB);
    const int blocks = (nB + PTS_PER_BLOCK - 1) / PTS_PER_BLOCK;
    mlp32_phase<<<dim3(blocks), dim3(BLOCK), 0, stream>>>(
        feat, w1,b1,w2,b2,w3,b3,
        cw1,cb1,cw2,cb2,cw3,cb3,cw4,cb4, out, nB);
  } else if (ws_size >= need){
    dim3 ga((nB + CH - 1) / CH, 16);
    hash_phase_f32<<<ga, dim3(512), 0, stream>>>(xin, tab, (unsigned int*)d_ws, nB);
    const int blocks = (nB + PTS_PER_BLOCK - 1) / PTS_PER_BLOCK;
    mlp32_phase<<<dim3(blocks), dim3(BLOCK), 0, stream>>>(
        (const unsigned int*)d_ws, w1,b1,w2,b2,w3,b3,
        cw1,cb1,cw2,cb2,cw3,cb3,cw4,cb4, out, nB);
  } else {
    const int blocks = (nB + BLOCK - 1) / BLOCK;
    nerf_fused<<<dim3(blocks), dim3(BLOCK), 0, stream>>>(
        xin, tab, w1,b1,w2,b2,w3,b3,
        cw1,cb1,cw2,cb2,cw3,cb3,cw4,cb4, out, nB);
  }
}